// Round 1
// baseline (204.623 us; speedup 1.0000x reference)
//
#include <hip/hip_runtime.h>
#include <math.h>

// Problem constants
#define NB 8      // batch
#define NC 128    // channels
#define NH 64     // height
#define NW 64     // width
#define NP 1024   // npatch (32x32)
#define TWO_SIG2 5.12f   // 2*(0.05*32)^2

// ws layout (in floats):
//   xd  : [NB][2][NP][NC]   normalized diag-pixel features   (2,097,152 f = 8 MB)
//   corr: [NB*2][NP][NP]    patch correlation matrices       (16,777,216 f = 64 MB)
//   rsum: [NB][3][NP]       exp row-sums (== col-sums by symmetry)  (24,576 f)
static const size_t XD_OFF   = 0;
static const size_t CORR_OFF = (size_t)NB * 2 * NP * NC;
static const size_t RSUM_OFF = CORR_OFF + (size_t)NB * 2 * NP * NP;

__device__ __forceinline__ int iabs_(int v) { return v < 0 ? -v : v; }

// Insert v into sorted-descending triple (A >= Bq >= Cq)
#define INSERT3(v, A, Bq, Cq)                \
  {                                          \
    const float _c1 = fminf(A, (v));         \
    A = fmaxf(A, (v));                       \
    const float _c2 = fminf(Bq, _c1);        \
    Bq = fmaxf(Bq, _c1);                     \
    Cq = fmaxf(Cq, _c2);                     \
  }

// Merge two sorted-descending triples (a into a)
#define MERGE3(a0, a1, a2, b0, b1, b2)       \
  {                                          \
    const float _x1 = fmaxf(a0, b0);         \
    const float _y1 = fminf(a0, b0);         \
    const float _x2 = fmaxf(a1, b1);         \
    const float _z  = fmaxf(a2, b2);         \
    a0 = _x1;                                \
    a1 = fmaxf(_y1, _x2);                    \
    a2 = fmaxf(fminf(_y1, _x2), _z);         \
  }

// ---------------------------------------------------------------------------
// K1: L2-normalize over channels at the two diagonal pixels of each 2x2 patch
//     and write transposed xd[b][p][n][c] (c contiguous).
// grid (16 chunks of 64 patches, p=2, b=8), block 256
// ---------------------------------------------------------------------------
__global__ __launch_bounds__(256) void k1_norm(const float* __restrict__ x,
                                               float* __restrict__ xd) {
  __shared__ __align__(16) float tile[NC * 65];  // [c][pix], pad 65 kills phase-2 conflicts
  const int chunk = blockIdx.x;
  const int p = blockIdx.y;
  const int b = blockIdx.z;
  const int t = threadIdx.x;
  const int pix = t & 63;
  const int cw = t >> 6;
  const int nbase = chunk * 64;

  {
    const int n = nbase + pix;
    const int i = ((n >> 5) << 1) + p;   // 2r + p
    const int j = ((n & 31) << 1) + p;   // 2c + p
    const float* xb = x + (size_t)b * NC * NH * NW + (size_t)i * NW + j;
    for (int cc = 0; cc < 32; ++cc) {
      const int c = (cc << 2) + cw;
      tile[c * 65 + pix] = xb[(size_t)c * NH * NW];
    }
  }
  __syncthreads();

  const int lane = t & 63;
  const int w = t >> 6;
  for (int pg = 0; pg < 16; ++pg) {
    const int pixel = (pg << 2) + w;     // each wave owns one pixel (128 channels)
    const float v0 = tile[lane * 65 + pixel];
    const float v1 = tile[(lane + 64) * 65 + pixel];
    float ss = v0 * v0 + v1 * v1;
#pragma unroll
    for (int m = 32; m >= 1; m >>= 1) ss += __shfl_xor(ss, m, 64);
    const float inv = 1.0f / fmaxf(sqrtf(ss), 1e-12f);
    float* xr = xd + ((size_t)((b * 2 + p) * NP) + nbase + pixel) * NC;
    xr[lane] = v0 * inv;
    xr[lane + 64] = v1 * inv;
  }
}

// ---------------------------------------------------------------------------
// K2: corr[bp] = xd[bp] * xd[bp]^T   (1024x1024, K=128) fp32 tiled GEMM.
// 64x64 tile per block, 256 threads, each computes 4x4 outputs at stride 16
// (stride-16 col/row ownership keeps LDS b128 reads <=2-way bank-conflicted).
// grid (16 m-tiles, 16 n-tiles, 16 bp), block 256
// ---------------------------------------------------------------------------
__global__ __launch_bounds__(256) void k2_corr(const float* __restrict__ xd,
                                               float* __restrict__ corr) {
  __shared__ __align__(16) float As[64 * 132];  // row stride 132 (mult of 4 -> b128 aligned)
  __shared__ __align__(16) float Bs[64 * 132];
  const int t = threadIdx.x;
  const int m0 = blockIdx.x << 6;
  const int n0 = blockIdx.y << 6;
  const int bp = blockIdx.z;

  const float4* xa = (const float4*)(xd + ((size_t)bp * NP + n0) * NC);
  const float4* xb = (const float4*)(xd + ((size_t)bp * NP + m0) * NC);
#pragma unroll
  for (int it = 0; it < 8; ++it) {
    const int flat = (it << 8) + t;
    const int row = flat >> 5;       // 0..63
    const int kq = flat & 31;        // float4 index in row
    const float4 va = xa[row * 32 + kq];
    const float4 vb = xb[row * 32 + kq];
    *(float4*)(&As[row * 132 + (kq << 2)]) = va;
    *(float4*)(&Bs[row * 132 + (kq << 2)]) = vb;
  }
  __syncthreads();

  const int tx = t & 15;
  const int ty = t >> 4;
  float acc[4][4];
#pragma unroll
  for (int i = 0; i < 4; ++i)
#pragma unroll
    for (int j = 0; j < 4; ++j) acc[i][j] = 0.f;

#pragma unroll 8
  for (int k4 = 0; k4 < 128; k4 += 4) {
    float4 a[4], bv[4];
#pragma unroll
    for (int i = 0; i < 4; ++i) a[i] = *(const float4*)(&As[(ty + 16 * i) * 132 + k4]);
#pragma unroll
    for (int j = 0; j < 4; ++j) bv[j] = *(const float4*)(&Bs[(tx + 16 * j) * 132 + k4]);
#pragma unroll
    for (int i = 0; i < 4; ++i)
#pragma unroll
      for (int j = 0; j < 4; ++j)
        acc[i][j] += a[i].x * bv[j].x + a[i].y * bv[j].y + a[i].z * bv[j].z + a[i].w * bv[j].w;
  }

  float* crow = corr + (size_t)bp * NP * NP;
#pragma unroll
  for (int i = 0; i < 4; ++i) {
    const int rr = n0 + ty + 16 * i;
#pragma unroll
    for (int j = 0; j < 4; ++j)
      crow[(size_t)rr * NP + (m0 + tx + 16 * j)] = acc[i][j];
  }
}

// ---------------------------------------------------------------------------
// K3: column sums of E_k = exp(alpha*(1-g)*c_k) for k=0 (corr0), 1 (corr1),
//     2 (avg). By symmetry these equal the row sums the softmaxes need.
// Block handles 16 rows x all 1024 cols; thread owns 4 fixed cols; atomics
// across the 64 row-chunks. grid (8*64), block 256
// ---------------------------------------------------------------------------
__global__ __launch_bounds__(256) void k3_sums(const float* __restrict__ corr,
                                               const float* __restrict__ alpha_p,
                                               float* __restrict__ rsum) {
  __shared__ float er[32];
  const int t = threadIdx.x;
  if (t < 32) er[t] = __expf(-(float)(t * t) / TWO_SIG2);
  __syncthreads();

  const int chunk = blockIdx.x & 63;
  const int b = blockIdx.x >> 6;
  const float alpha = *alpha_p;
  const int m = t << 2;
  const int rm = m >> 5;
  const int cm = m & 31;

  float acc0[4] = {0, 0, 0, 0}, acc1[4] = {0, 0, 0, 0}, acc2[4] = {0, 0, 0, 0};
  const float4* p0 = (const float4*)(corr + ((size_t)(b * 2 + 0) * NP + chunk * 16) * NP) + t;
  const float4* p1 = (const float4*)(corr + ((size_t)(b * 2 + 1) * NP + chunk * 16) * NP) + t;

  for (int r = 0; r < 16; ++r) {
    const int n = chunk * 16 + r;
    const int rn = n >> 5, cn = n & 31;
    const float4 v0 = p0[(size_t)r * 256];
    const float4 v1 = p1[(size_t)r * 256];
    float c0[4], c1[4];
    *(float4*)c0 = v0;
    *(float4*)c1 = v1;
    const float gr = er[iabs_(rn - rm)];
#pragma unroll
    for (int u = 0; u < 4; ++u) {
      const float g = gr * er[iabs_(cn - (cm + u))];
      const float f = alpha * (1.f - g);
      acc0[u] += __expf(f * c0[u]);
      acc1[u] += __expf(f * c1[u]);
      acc2[u] += __expf(f * 0.5f * (c0[u] + c1[u]));
    }
  }

  float* rsb = rsum + (size_t)b * 3 * NP + m;
#pragma unroll
  for (int u = 0; u < 4; ++u) {
    atomicAdd(&rsb[u], acc0[u]);
    atomicAdd(&rsb[NP + u], acc1[u]);
    atomicAdd(&rsb[2 * NP + u], acc2[u]);
  }
}

// ---------------------------------------------------------------------------
// K4: per (b, n): S_k[m] = E_k^2 / (rsum_k[n]*rsum_k[m]); top-3 over m for the
// 3 channels; scatter to output spatial positions.
// grid (8*1024), block 256 (thread owns 4 cols)
// ---------------------------------------------------------------------------
__global__ __launch_bounds__(256) void k4_topk(const float* __restrict__ corr,
                                               const float* __restrict__ alpha_p,
                                               const float* __restrict__ rsum,
                                               float* __restrict__ out) {
  __shared__ float er[32];
  __shared__ float red[4][9];
  const int t = threadIdx.x;
  if (t < 32) er[t] = __expf(-(float)(t * t) / TWO_SIG2);
  __syncthreads();

  const int n = blockIdx.x & (NP - 1);
  const int b = blockIdx.x >> 10;
  const float alpha = *alpha_p;
  const int rn = n >> 5, cn = n & 31;

  const float4 v0 = ((const float4*)(corr + ((size_t)(b * 2 + 0) * NP + n) * NP))[t];
  const float4 v1 = ((const float4*)(corr + ((size_t)(b * 2 + 1) * NP + n) * NP))[t];
  const float* rsb = rsum + (size_t)b * 3 * NP;
  const float ir0 = 1.f / rsb[n];
  const float ir1 = 1.f / rsb[NP + n];
  const float ir2 = 1.f / rsb[2 * NP + n];
  const float4 w0 = ((const float4*)(rsb))[t];
  const float4 w1 = ((const float4*)(rsb + NP))[t];
  const float4 w2 = ((const float4*)(rsb + 2 * NP))[t];

  float c0[4], c1[4], s0[4], s1[4], s2[4];
  *(float4*)c0 = v0;
  *(float4*)c1 = v1;
  *(float4*)s0 = w0;
  *(float4*)s1 = w1;
  *(float4*)s2 = w2;

  float a0[3], a1[3], a2[3];
#pragma unroll
  for (int k = 0; k < 3; ++k) { a0[k] = -1e30f; a1[k] = -1e30f; a2[k] = -1e30f; }

  const int m0 = t << 2;
  const int rm = m0 >> 5;
  const int cmb = m0 & 31;
  const float gr = er[iabs_(rn - rm)];
#pragma unroll
  for (int u = 0; u < 4; ++u) {
    const float g = gr * er[iabs_(cn - (cmb + u))];
    const float f = alpha * (1.f - g);
    const float e0 = __expf(f * c0[u]);
    const float e1 = __expf(f * c1[u]);
    const float e2 = __expf(f * 0.5f * (c0[u] + c1[u]));
    const float q0 = e0 * e0 * ir0 / s0[u];
    const float q1 = e1 * e1 * ir1 / s1[u];
    const float q2 = e2 * e2 * ir2 / s2[u];
    INSERT3(q0, a0[0], a1[0], a2[0]);
    INSERT3(q1, a0[1], a1[1], a2[1]);
    INSERT3(q2, a0[2], a1[2], a2[2]);
  }

#pragma unroll
  for (int off = 1; off < 64; off <<= 1) {
#pragma unroll
    for (int k = 0; k < 3; ++k) {
      const float b0 = __shfl_xor(a0[k], off, 64);
      const float b1 = __shfl_xor(a1[k], off, 64);
      const float b2 = __shfl_xor(a2[k], off, 64);
      MERGE3(a0[k], a1[k], a2[k], b0, b1, b2);
    }
  }

  const int w = t >> 6;
  if ((t & 63) == 0) {
#pragma unroll
    for (int k = 0; k < 3; ++k) {
      red[w][k * 3 + 0] = a0[k];
      red[w][k * 3 + 1] = a1[k];
      red[w][k * 3 + 2] = a2[k];
    }
  }
  __syncthreads();

  if (t == 0) {
    float f0[3], f1[3], f2[3];
#pragma unroll
    for (int k = 0; k < 3; ++k) {
      f0[k] = red[0][k * 3 + 0];
      f1[k] = red[0][k * 3 + 1];
      f2[k] = red[0][k * 3 + 2];
      for (int ww = 1; ww < 4; ++ww) {
        const float b0 = red[ww][k * 3 + 0];
        const float b1 = red[ww][k * 3 + 1];
        const float b2 = red[ww][k * 3 + 2];
        MERGE3(f0[k], f1[k], f2[k], b0, b1, b2);
      }
    }
    // scatter: channel 0 -> (2r,2c); 1 -> (2r+1,2c+1); 2 -> (2r,2c+1) and (2r+1,2c)
    float* ob = out + (size_t)b * 3 * (NH * NW);
    const int i00 = ((rn << 1) * NW) + (cn << 1);
#pragma unroll
    for (int tt = 0; tt < 3; ++tt) {
      float* op = ob + (size_t)tt * (NH * NW);
      const float r0 = (tt == 0) ? f0[0] : (tt == 1) ? f1[0] : f2[0];
      const float r1 = (tt == 0) ? f0[1] : (tt == 1) ? f1[1] : f2[1];
      const float r2 = (tt == 0) ? f0[2] : (tt == 1) ? f1[2] : f2[2];
      op[i00] = r0;            // (2r, 2c)
      op[i00 + NW + 1] = r1;   // (2r+1, 2c+1)
      op[i00 + 1] = r2;        // (2r, 2c+1)
      op[i00 + NW] = r2;       // (2r+1, 2c)
    }
  }
}

extern "C" void kernel_launch(void* const* d_in, const int* in_sizes, int n_in,
                              void* d_out, int out_size, void* d_ws, size_t ws_size,
                              hipStream_t stream) {
  const float* x = (const float*)d_in[0];
  const float* alpha = (const float*)d_in[1];
  float* out = (float*)d_out;
  float* ws = (float*)d_ws;

  float* xd = ws + XD_OFF;
  float* corr = ws + CORR_OFF;
  float* rsum = ws + RSUM_OFF;

  hipMemsetAsync(rsum, 0, (size_t)NB * 3 * NP * sizeof(float), stream);
  k1_norm<<<dim3(16, 2, NB), 256, 0, stream>>>(x, xd);
  k2_corr<<<dim3(16, 16, NB * 2), 256, 0, stream>>>(xd, corr);
  k3_sums<<<dim3(NB * 64), 256, 0, stream>>>(corr, alpha, rsum);
  k4_topk<<<dim3(NB * NP), 256, 0, stream>>>(corr, alpha, rsum, out);
}

// Round 2
// 127.472 us; speedup vs baseline: 1.6052x; 1.6052x over previous
//
#include <hip/hip_runtime.h>
#include <hip/hip_bf16.h>
#include <math.h>

// Problem constants
#define NB 8      // batch
#define NC 128    // channels
#define NH 64     // height
#define NW 64     // width
#define NP 1024   // npatch (32x32)
#define TWO_SIG2 5.12f   // 2*(0.05*32)^2

// ws layout (bytes):
//   corr : [NB*2][NP][NP] fp32   = 64 MB   (offset 0)
//   xd   : [NB*2][NP][NC] bf16   = 4 MB
//   rsum : [NB][3][NP]    fp32   = 96 KB
static const size_t CORR_OFF_B = 0;
static const size_t XD_OFF_B   = (size_t)NB * 2 * NP * NP * 4;
static const size_t RSUM_OFF_B = XD_OFF_B + (size_t)NB * 2 * NP * NC * 2;

typedef __bf16 bf16x8 __attribute__((ext_vector_type(8)));
typedef float f32x4 __attribute__((ext_vector_type(4)));

__device__ __forceinline__ int iabs_(int v) { return v < 0 ? -v : v; }

// Insert v into sorted-descending triple (A >= Bq >= Cq)
#define INSERT3(v, A, Bq, Cq)                \
  {                                          \
    const float _c1 = fminf(A, (v));         \
    A = fmaxf(A, (v));                       \
    const float _c2 = fminf(Bq, _c1);        \
    Bq = fmaxf(Bq, _c1);                     \
    Cq = fmaxf(Cq, _c2);                     \
  }

// Merge two sorted-descending triples (a into a)
#define MERGE3(a0, a1, a2, b0, b1, b2)       \
  {                                          \
    const float _x1 = fmaxf(a0, b0);         \
    const float _y1 = fminf(a0, b0);         \
    const float _x2 = fmaxf(a1, b1);         \
    const float _z  = fmaxf(a2, b2);         \
    a0 = _x1;                                \
    a1 = fmaxf(_y1, _x2);                    \
    a2 = fmaxf(fminf(_y1, _x2), _z);         \
  }

// ---------------------------------------------------------------------------
// K1: L2-normalize over channels at the two diagonal pixels of each 2x2 patch
//     and write transposed xd[b][p][n][c] (c contiguous) as bf16.
// grid (16 chunks of 64 patches, p=2, b=8), block 256
// ---------------------------------------------------------------------------
__global__ __launch_bounds__(256) void k1_norm(const float* __restrict__ x,
                                               __hip_bfloat16* __restrict__ xd) {
  __shared__ __align__(16) float tile[NC * 65];
  const int chunk = blockIdx.x;
  const int p = blockIdx.y;
  const int b = blockIdx.z;
  const int t = threadIdx.x;
  const int pix = t & 63;
  const int cw = t >> 6;
  const int nbase = chunk * 64;

  {
    const int n = nbase + pix;
    const int i = ((n >> 5) << 1) + p;   // 2r + p
    const int j = ((n & 31) << 1) + p;   // 2c + p
    const float* xb = x + (size_t)b * NC * NH * NW + (size_t)i * NW + j;
    for (int cc = 0; cc < 32; ++cc) {
      const int c = (cc << 2) + cw;
      tile[c * 65 + pix] = xb[(size_t)c * NH * NW];
    }
  }
  __syncthreads();

  const int lane = t & 63;
  const int w = t >> 6;
  for (int pg = 0; pg < 16; ++pg) {
    const int pixel = (pg << 2) + w;     // each wave owns one pixel (128 channels)
    const float v0 = tile[lane * 65 + pixel];
    const float v1 = tile[(lane + 64) * 65 + pixel];
    float ss = v0 * v0 + v1 * v1;
#pragma unroll
    for (int m = 32; m >= 1; m >>= 1) ss += __shfl_xor(ss, m, 64);
    const float inv = 1.0f / fmaxf(sqrtf(ss), 1e-12f);
    __hip_bfloat16* xr = xd + ((size_t)((b * 2 + p) * NP) + nbase + pixel) * NC;
    xr[lane] = __float2bfloat16(v0 * inv);
    xr[lane + 64] = __float2bfloat16(v1 * inv);
  }
}

// ---------------------------------------------------------------------------
// K2: corr[bp] = xd[bp] * xd[bp]^T  via bf16 MFMA 16x16x32, fp32 out.
// 128x128 tile/block, K=128 resident in LDS (no K-loop over tiles).
// LDS row pad +8 bf16 (16B) -> frag reads <=2-way bank aliased (free).
// grid (8 row-tiles, 8 col-tiles, 16 bp), block 256 (4 waves).
// ---------------------------------------------------------------------------
__global__ __launch_bounds__(256) void k2_corr(const ushort* __restrict__ xd,
                                               float* __restrict__ corr) {
  __shared__ __align__(16) __bf16 As[128 * 136];
  __shared__ __align__(16) __bf16 Bs[128 * 136];
  const int t = threadIdx.x;
  const int i0 = blockIdx.x << 7;  // output rows (n)
  const int j0 = blockIdx.y << 7;  // output cols (m)
  const int bp = blockIdx.z;

  const float4* ga = (const float4*)(xd + ((size_t)bp * NP + i0) * NC);
  const float4* gb = (const float4*)(xd + ((size_t)bp * NP + j0) * NC);
#pragma unroll
  for (int it = 0; it < 8; ++it) {
    const int f = (it << 8) + t;      // 16B chunk id, 0..2047
    const int r = f >> 4;             // row 0..127
    const int q = f & 15;             // 16B chunk within row
    const float4 va = ga[f];
    const float4 vb = gb[f];
    *(float4*)(&As[r * 136 + q * 8]) = va;
    *(float4*)(&Bs[r * 136 + q * 8]) = vb;
  }
  __syncthreads();

  const int wave = t >> 6;
  const int lane = t & 63;
  const int lrow = lane & 15;
  const int kq = lane >> 4;          // k-offset quarter: k = 8*kq (+32*kc)

  f32x4 acc[2][8];
#pragma unroll
  for (int rt = 0; rt < 2; ++rt)
#pragma unroll
    for (int ct = 0; ct < 8; ++ct)
#pragma unroll
      for (int u = 0; u < 4; ++u) acc[rt][ct][u] = 0.f;

#pragma unroll
  for (int kc = 0; kc < 4; ++kc) {
    const int kk = kc * 32 + (kq << 3);
    bf16x8 a[2], bfr[8];
#pragma unroll
    for (int rt = 0; rt < 2; ++rt)
      a[rt] = *(const bf16x8*)(&As[(wave * 32 + rt * 16 + lrow) * 136 + kk]);
#pragma unroll
    for (int ct = 0; ct < 8; ++ct)
      bfr[ct] = *(const bf16x8*)(&Bs[(ct * 16 + lrow) * 136 + kk]);
#pragma unroll
    for (int rt = 0; rt < 2; ++rt)
#pragma unroll
      for (int ct = 0; ct < 8; ++ct)
        acc[rt][ct] = __builtin_amdgcn_mfma_f32_16x16x32_bf16(a[rt], bfr[ct], acc[rt][ct], 0, 0, 0);
  }

  // C/D layout (m89-verified): col = lane&15, row = (lane>>4)*4 + reg
  float* cb = corr + (size_t)bp * NP * NP;
#pragma unroll
  for (int rt = 0; rt < 2; ++rt) {
#pragma unroll
    for (int reg = 0; reg < 4; ++reg) {
      const int n = i0 + wave * 32 + rt * 16 + kq * 4 + reg;
      float* rowp = cb + (size_t)n * NP + j0 + lrow;
#pragma unroll
      for (int ct = 0; ct < 8; ++ct)
        rowp[ct * 16] = acc[rt][ct][reg];
    }
  }
}

// ---------------------------------------------------------------------------
// K3: per-row sums of E_k = exp(alpha*(1-g)*c_k), k=0 (corr0), 1 (corr1),
//     2 (avg). Row sums == col sums by symmetry. NO atomics: one wave owns
//     4 full rows, shuffle-reduces. grid (8 b * 64 chunks), block 256.
// ---------------------------------------------------------------------------
__global__ __launch_bounds__(256) void k3_sums(const float* __restrict__ corr,
                                               const float* __restrict__ alpha_p,
                                               float* __restrict__ rsum) {
  __shared__ float er[32];
  const int t = threadIdx.x;
  if (t < 32) er[t] = __expf(-(float)(t * t) / TWO_SIG2);
  __syncthreads();

  const int chunk = blockIdx.x & 63;
  const int b = blockIdx.x >> 6;
  const float alpha = *alpha_p;
  const int wave = t >> 6;
  const int lane = t & 63;

  for (int rr = 0; rr < 4; ++rr) {
    const int n = chunk * 16 + wave * 4 + rr;
    const int rn = n >> 5, cn = n & 31;
    const float4* p0 = (const float4*)(corr + ((size_t)(b * 2 + 0) * NP + n) * NP);
    const float4* p1 = (const float4*)(corr + ((size_t)(b * 2 + 1) * NP + n) * NP);
    float s0 = 0.f, s1 = 0.f, s2 = 0.f;
#pragma unroll
    for (int it = 0; it < 4; ++it) {
      const int m4 = it * 64 + lane;
      const float4 v0 = p0[m4];
      const float4 v1 = p1[m4];
      float c0[4], c1[4];
      *(float4*)c0 = v0;
      *(float4*)c1 = v1;
      const int m = m4 << 2;
      const int rm = m >> 5, cm = m & 31;
      const float gr = er[iabs_(rn - rm)];
#pragma unroll
      for (int u = 0; u < 4; ++u) {
        const float g = gr * er[iabs_(cn - (cm + u))];
        const float f = alpha * (1.f - g);
        s0 += __expf(f * c0[u]);
        s1 += __expf(f * c1[u]);
        s2 += __expf(f * 0.5f * (c0[u] + c1[u]));
      }
    }
#pragma unroll
    for (int off = 32; off >= 1; off >>= 1) {
      s0 += __shfl_xor(s0, off, 64);
      s1 += __shfl_xor(s1, off, 64);
      s2 += __shfl_xor(s2, off, 64);
    }
    if (lane == 0) {
      float* rsb = rsum + (size_t)b * 3 * NP;
      rsb[n] = s0;
      rsb[NP + n] = s1;
      rsb[2 * NP + n] = s2;
    }
  }
}

// ---------------------------------------------------------------------------
// K4: per (b, n): S_k[m] = E_k^2 / (rsum_k[n]*rsum_k[m]); top-3 over m for the
// 3 channels; scatter to output spatial positions.
// grid (8*1024), block 256 (thread owns 4 cols)
// ---------------------------------------------------------------------------
__global__ __launch_bounds__(256) void k4_topk(const float* __restrict__ corr,
                                               const float* __restrict__ alpha_p,
                                               const float* __restrict__ rsum,
                                               float* __restrict__ out) {
  __shared__ float er[32];
  __shared__ float red[4][9];
  const int t = threadIdx.x;
  if (t < 32) er[t] = __expf(-(float)(t * t) / TWO_SIG2);
  __syncthreads();

  const int n = blockIdx.x & (NP - 1);
  const int b = blockIdx.x >> 10;
  const float alpha = *alpha_p;
  const int rn = n >> 5, cn = n & 31;

  const float4 v0 = ((const float4*)(corr + ((size_t)(b * 2 + 0) * NP + n) * NP))[t];
  const float4 v1 = ((const float4*)(corr + ((size_t)(b * 2 + 1) * NP + n) * NP))[t];
  const float* rsb = rsum + (size_t)b * 3 * NP;
  const float ir0 = 1.f / rsb[n];
  const float ir1 = 1.f / rsb[NP + n];
  const float ir2 = 1.f / rsb[2 * NP + n];
  const float4 w0 = ((const float4*)(rsb))[t];
  const float4 w1 = ((const float4*)(rsb + NP))[t];
  const float4 w2 = ((const float4*)(rsb + 2 * NP))[t];

  float c0[4], c1[4], s0[4], s1[4], s2[4];
  *(float4*)c0 = v0;
  *(float4*)c1 = v1;
  *(float4*)s0 = w0;
  *(float4*)s1 = w1;
  *(float4*)s2 = w2;

  float a0[3], a1[3], a2[3];
#pragma unroll
  for (int k = 0; k < 3; ++k) { a0[k] = -1e30f; a1[k] = -1e30f; a2[k] = -1e30f; }

  const int m0 = t << 2;
  const int rm = m0 >> 5;
  const int cmb = m0 & 31;
  const float gr = er[iabs_(rn - rm)];
#pragma unroll
  for (int u = 0; u < 4; ++u) {
    const float g = gr * er[iabs_(cn - (cmb + u))];
    const float f = alpha * (1.f - g);
    const float e0 = __expf(f * c0[u]);
    const float e1 = __expf(f * c1[u]);
    const float e2 = __expf(f * 0.5f * (c0[u] + c1[u]));
    const float q0 = e0 * e0 * ir0 / s0[u];
    const float q1 = e1 * e1 * ir1 / s1[u];
    const float q2 = e2 * e2 * ir2 / s2[u];
    INSERT3(q0, a0[0], a1[0], a2[0]);
    INSERT3(q1, a0[1], a1[1], a2[1]);
    INSERT3(q2, a0[2], a1[2], a2[2]);
  }

#pragma unroll
  for (int off = 1; off < 64; off <<= 1) {
#pragma unroll
    for (int k = 0; k < 3; ++k) {
      const float b0 = __shfl_xor(a0[k], off, 64);
      const float b1 = __shfl_xor(a1[k], off, 64);
      const float b2 = __shfl_xor(a2[k], off, 64);
      MERGE3(a0[k], a1[k], a2[k], b0, b1, b2);
    }
  }

  const int w = t >> 6;
  if ((t & 63) == 0) {
#pragma unroll
    for (int k = 0; k < 3; ++k) {
      red[w][k * 3 + 0] = a0[k];
      red[w][k * 3 + 1] = a1[k];
      red[w][k * 3 + 2] = a2[k];
    }
  }
  __syncthreads();

  if (t == 0) {
    float f0[3], f1[3], f2[3];
#pragma unroll
    for (int k = 0; k < 3; ++k) {
      f0[k] = red[0][k * 3 + 0];
      f1[k] = red[0][k * 3 + 1];
      f2[k] = red[0][k * 3 + 2];
      for (int ww = 1; ww < 4; ++ww) {
        const float b0 = red[ww][k * 3 + 0];
        const float b1 = red[ww][k * 3 + 1];
        const float b2 = red[ww][k * 3 + 2];
        MERGE3(f0[k], f1[k], f2[k], b0, b1, b2);
      }
    }
    // scatter: channel 0 -> (2r,2c); 1 -> (2r+1,2c+1); 2 -> (2r,2c+1) and (2r+1,2c)
    float* ob = out + (size_t)b * 3 * (NH * NW);
    const int i00 = ((rn << 1) * NW) + (cn << 1);
#pragma unroll
    for (int tt = 0; tt < 3; ++tt) {
      float* op = ob + (size_t)tt * (NH * NW);
      const float r0 = (tt == 0) ? f0[0] : (tt == 1) ? f1[0] : f2[0];
      const float r1 = (tt == 0) ? f0[1] : (tt == 1) ? f1[1] : f2[1];
      const float r2 = (tt == 0) ? f0[2] : (tt == 1) ? f1[2] : f2[2];
      op[i00] = r0;            // (2r, 2c)
      op[i00 + NW + 1] = r1;   // (2r+1, 2c+1)
      op[i00 + 1] = r2;        // (2r, 2c+1)
      op[i00 + NW] = r2;       // (2r+1, 2c)
    }
  }
}

extern "C" void kernel_launch(void* const* d_in, const int* in_sizes, int n_in,
                              void* d_out, int out_size, void* d_ws, size_t ws_size,
                              hipStream_t stream) {
  const float* x = (const float*)d_in[0];
  const float* alpha = (const float*)d_in[1];
  float* out = (float*)d_out;
  char* ws = (char*)d_ws;

  float* corr = (float*)(ws + CORR_OFF_B);
  __hip_bfloat16* xd = (__hip_bfloat16*)(ws + XD_OFF_B);
  float* rsum = (float*)(ws + RSUM_OFF_B);

  k1_norm<<<dim3(16, 2, NB), 256, 0, stream>>>(x, xd);
  k2_corr<<<dim3(8, 8, NB * 2), 256, 0, stream>>>((const ushort*)xd, corr);
  k3_sums<<<dim3(NB * 64), 256, 0, stream>>>(corr, alpha, rsum);
  k4_topk<<<dim3(NB * NP), 256, 0, stream>>>(corr, alpha, rsum, out);
}

// Round 3
// 119.098 us; speedup vs baseline: 1.7181x; 1.0703x over previous
//
#include <hip/hip_runtime.h>
#include <hip/hip_bf16.h>
#include <math.h>

// Problem constants
#define NB 8      // batch
#define NC 128    // channels
#define NH 64     // height
#define NW 64     // width
#define NP 1024   // npatch (32x32)
#define TWO_SIG2 5.12f   // 2*(0.05*32)^2

// ws layout (bytes):
//   rsum : [NB][3][NP] fp32                 =  96 KB
//   pbuf : [NB*NP][3ch][4 part][3] fp32     = 1.18 MB  (top-3 partials)
//   xd   : [NB*2][NP][NC] bf16              =  4 MB
static const size_t RSUM_OFF_B = 0;
static const size_t PBUF_OFF_B = (size_t)NB * 3 * NP * 4;
static const size_t XD_OFF_B   = PBUF_OFF_B + (size_t)NB * NP * 3 * 4 * 3 * 4;

typedef __bf16 bf16x8 __attribute__((ext_vector_type(8)));
typedef float f32x4 __attribute__((ext_vector_type(4)));

__device__ __forceinline__ int iabs_(int v) { return v < 0 ? -v : v; }

// Insert v into sorted-descending triple (A >= Bq >= Cq)
#define INSERT3(v, A, Bq, Cq)                \
  {                                          \
    const float _c1 = fminf(A, (v));         \
    A = fmaxf(A, (v));                       \
    const float _c2 = fminf(Bq, _c1);        \
    Bq = fmaxf(Bq, _c1);                     \
    Cq = fmaxf(Cq, _c2);                     \
  }

// Merge two sorted-descending triples (a <- merge(a,b))
#define MERGE3(a0, a1, a2, b0, b1, b2)       \
  {                                          \
    const float _x1 = fmaxf(a0, b0);         \
    const float _y1 = fminf(a0, b0);         \
    const float _x2 = fmaxf(a1, b1);         \
    const float _z  = fmaxf(a2, b2);         \
    a0 = _x1;                                \
    a1 = fmaxf(_y1, _x2);                    \
    a2 = fmaxf(fminf(_y1, _x2), _z);         \
  }

// ---------------------------------------------------------------------------
// K1: L2-normalize over channels at the two diagonal pixels of each 2x2 patch
//     and write transposed xd[b][p][n][c] (c contiguous) as bf16.
// grid (16 chunks of 64 patches, p=2, b=8), block 256
// ---------------------------------------------------------------------------
__global__ __launch_bounds__(256) void k1_norm(const float* __restrict__ x,
                                               __hip_bfloat16* __restrict__ xd) {
  __shared__ __align__(16) float tile[NC * 65];
  const int chunk = blockIdx.x;
  const int p = blockIdx.y;
  const int b = blockIdx.z;
  const int t = threadIdx.x;
  const int pix = t & 63;
  const int cw = t >> 6;
  const int nbase = chunk * 64;

  {
    const int n = nbase + pix;
    const int i = ((n >> 5) << 1) + p;   // 2r + p
    const int j = ((n & 31) << 1) + p;   // 2c + p
    const float* xb = x + (size_t)b * NC * NH * NW + (size_t)i * NW + j;
    for (int cc = 0; cc < 32; ++cc) {
      const int c = (cc << 2) + cw;
      tile[c * 65 + pix] = xb[(size_t)c * NH * NW];
    }
  }
  __syncthreads();

  const int lane = t & 63;
  const int w = t >> 6;
  for (int pg = 0; pg < 16; ++pg) {
    const int pixel = (pg << 2) + w;     // each wave owns one pixel (128 channels)
    const float v0 = tile[lane * 65 + pixel];
    const float v1 = tile[(lane + 64) * 65 + pixel];
    float ss = v0 * v0 + v1 * v1;
#pragma unroll
    for (int m = 32; m >= 1; m >>= 1) ss += __shfl_xor(ss, m, 64);
    const float inv = 1.0f / fmaxf(sqrtf(ss), 1e-12f);
    __hip_bfloat16* xr = xd + ((size_t)((b * 2 + p) * NP) + nbase + pixel) * NC;
    xr[lane] = __float2bfloat16(v0 * inv);
    xr[lane + 64] = __float2bfloat16(v1 * inv);
  }
}

// ---------------------------------------------------------------------------
// K2: fused corr (MFMA, in registers) -> mask -> exp -> row sums.
// Block: 64 rows x 256 cols, both p-planes. corr is never materialized.
// grid (4 colchunk, 16 rowtile, 8 b), block 256 (4 waves; wave owns 16 rows)
// ---------------------------------------------------------------------------
__global__ __launch_bounds__(256) void k2_sums(const ushort* __restrict__ xd,
                                               const float* __restrict__ alpha_p,
                                               float* __restrict__ rsum) {
  __shared__ __align__(16) __bf16 As[2][64 * 136];
  __shared__ __align__(16) __bf16 Bs[2][64 * 136];
  __shared__ float er[32];
  const int t = threadIdx.x;
  if (t < 32) er[t] = __expf(-(float)(t * t) / TWO_SIG2);

  const int cchunk = blockIdx.x;
  const int rowtile = blockIdx.y;
  const int b = blockIdx.z;
  const int i0 = rowtile << 6;
  const int jb = cchunk << 8;
  const float alpha = *alpha_p;

  // stage A (both planes): 64 rows x 128 ch bf16
#pragma unroll
  for (int pl = 0; pl < 2; ++pl) {
    const float4* ga = (const float4*)(xd + ((size_t)(b * 2 + pl) * NP + i0) * NC);
#pragma unroll
    for (int it = 0; it < 4; ++it) {
      const int f = (it << 8) + t;
      const int r = f >> 4, q = f & 15;
      *(float4*)(&As[pl][r * 136 + q * 8]) = ga[f];
    }
  }

  const int wave = t >> 6;
  const int lane = t & 63;
  const int lrow = lane & 15;
  const int kq = lane >> 4;

  float sums[3][4];
#pragma unroll
  for (int ch = 0; ch < 3; ++ch)
#pragma unroll
    for (int reg = 0; reg < 4; ++reg) sums[ch][reg] = 0.f;

  for (int sc = 0; sc < 4; ++sc) {
    const int j0 = jb + (sc << 6);
    __syncthreads();
#pragma unroll
    for (int pl = 0; pl < 2; ++pl) {
      const float4* gb = (const float4*)(xd + ((size_t)(b * 2 + pl) * NP + j0) * NC);
#pragma unroll
      for (int it = 0; it < 4; ++it) {
        const int f = (it << 8) + t;
        const int r = f >> 4, q = f & 15;
        *(float4*)(&Bs[pl][r * 136 + q * 8]) = gb[f];
      }
    }
    __syncthreads();

    f32x4 acc[2][4];
#pragma unroll
    for (int pl = 0; pl < 2; ++pl)
#pragma unroll
      for (int ct = 0; ct < 4; ++ct)
#pragma unroll
        for (int u = 0; u < 4; ++u) acc[pl][ct][u] = 0.f;

#pragma unroll
    for (int kc = 0; kc < 4; ++kc) {
      const int kk = kc * 32 + (kq << 3);
      const bf16x8 a0 = *(const bf16x8*)(&As[0][(wave * 16 + lrow) * 136 + kk]);
      const bf16x8 a1 = *(const bf16x8*)(&As[1][(wave * 16 + lrow) * 136 + kk]);
#pragma unroll
      for (int ct = 0; ct < 4; ++ct) {
        const bf16x8 b0 = *(const bf16x8*)(&Bs[0][(ct * 16 + lrow) * 136 + kk]);
        const bf16x8 b1 = *(const bf16x8*)(&Bs[1][(ct * 16 + lrow) * 136 + kk]);
        acc[0][ct] = __builtin_amdgcn_mfma_f32_16x16x32_bf16(a0, b0, acc[0][ct], 0, 0, 0);
        acc[1][ct] = __builtin_amdgcn_mfma_f32_16x16x32_bf16(a1, b1, acc[1][ct], 0, 0, 0);
      }
    }

    // mask + exp + accumulate row sums
#pragma unroll
    for (int ct = 0; ct < 4; ++ct) {
      const int m = j0 + ct * 16 + lrow;
      const int rm = m >> 5, cm = m & 31;
#pragma unroll
      for (int reg = 0; reg < 4; ++reg) {
        const int n = i0 + wave * 16 + kq * 4 + reg;
        const int rn = n >> 5, cn = n & 31;
        const float g = er[iabs_(rn - rm)] * er[iabs_(cn - cm)];
        const float fm = alpha * (1.f - g);
        const float c0 = acc[0][ct][reg];
        const float c1 = acc[1][ct][reg];
        sums[0][reg] += __expf(fm * c0);
        sums[1][reg] += __expf(fm * c1);
        sums[2][reg] += __expf(fm * 0.5f * (c0 + c1));
      }
    }
  }

  // reduce across the 16 col-lanes (same rows)
#pragma unroll
  for (int off = 1; off < 16; off <<= 1)
#pragma unroll
    for (int ch = 0; ch < 3; ++ch)
#pragma unroll
      for (int reg = 0; reg < 4; ++reg)
        sums[ch][reg] += __shfl_xor(sums[ch][reg], off, 64);

  if (lrow == 0) {
#pragma unroll
    for (int ch = 0; ch < 3; ++ch)
#pragma unroll
      for (int reg = 0; reg < 4; ++reg) {
        const int n = i0 + wave * 16 + kq * 4 + reg;
        atomicAdd(&rsum[((size_t)b * 3 + ch) * NP + n], sums[ch][reg]);
      }
  }
}

// ---------------------------------------------------------------------------
// K4: fused corr recompute -> mask -> exp -> S = E^2 * ir_n * ir_m -> online
// top-3 per row per channel; writes per-colchunk partials.
// grid (4 colchunk, 16 rowtile, 8 b), block 256
// ---------------------------------------------------------------------------
__global__ __launch_bounds__(256) void k4_topk(const ushort* __restrict__ xd,
                                               const float* __restrict__ alpha_p,
                                               const float* __restrict__ rsum,
                                               float* __restrict__ pbuf) {
  __shared__ __align__(16) __bf16 As[2][64 * 136];
  __shared__ __align__(16) __bf16 Bs[2][64 * 136];
  __shared__ float er[32];
  __shared__ float rsr[3][64];    // 1/rsum over this block's rows
  __shared__ float rsc[3][256];   // 1/rsum over this block's cols
  const int t = threadIdx.x;
  if (t < 32) er[t] = __expf(-(float)(t * t) / TWO_SIG2);

  const int cchunk = blockIdx.x;
  const int rowtile = blockIdx.y;
  const int b = blockIdx.z;
  const int i0 = rowtile << 6;
  const int jb = cchunk << 8;
  const float alpha = *alpha_p;

  if (t < 192) {
    const int ch = t >> 6, r = t & 63;
    rsr[ch][r] = 1.0f / rsum[((size_t)b * 3 + ch) * NP + i0 + r];
  }
#pragma unroll
  for (int ch = 0; ch < 3; ++ch)
    rsc[ch][t] = 1.0f / rsum[((size_t)b * 3 + ch) * NP + jb + t];

#pragma unroll
  for (int pl = 0; pl < 2; ++pl) {
    const float4* ga = (const float4*)(xd + ((size_t)(b * 2 + pl) * NP + i0) * NC);
#pragma unroll
    for (int it = 0; it < 4; ++it) {
      const int f = (it << 8) + t;
      const int r = f >> 4, q = f & 15;
      *(float4*)(&As[pl][r * 136 + q * 8]) = ga[f];
    }
  }

  const int wave = t >> 6;
  const int lane = t & 63;
  const int lrow = lane & 15;
  const int kq = lane >> 4;

  float tA[3][4], tB[3][4], tC[3][4];
#pragma unroll
  for (int ch = 0; ch < 3; ++ch)
#pragma unroll
    for (int reg = 0; reg < 4; ++reg) { tA[ch][reg] = -1e30f; tB[ch][reg] = -1e30f; tC[ch][reg] = -1e30f; }

  for (int sc = 0; sc < 4; ++sc) {
    const int j0 = jb + (sc << 6);
    __syncthreads();
#pragma unroll
    for (int pl = 0; pl < 2; ++pl) {
      const float4* gb = (const float4*)(xd + ((size_t)(b * 2 + pl) * NP + j0) * NC);
#pragma unroll
      for (int it = 0; it < 4; ++it) {
        const int f = (it << 8) + t;
        const int r = f >> 4, q = f & 15;
        *(float4*)(&Bs[pl][r * 136 + q * 8]) = gb[f];
      }
    }
    __syncthreads();

    f32x4 acc[2][4];
#pragma unroll
    for (int pl = 0; pl < 2; ++pl)
#pragma unroll
      for (int ct = 0; ct < 4; ++ct)
#pragma unroll
        for (int u = 0; u < 4; ++u) acc[pl][ct][u] = 0.f;

#pragma unroll
    for (int kc = 0; kc < 4; ++kc) {
      const int kk = kc * 32 + (kq << 3);
      const bf16x8 a0 = *(const bf16x8*)(&As[0][(wave * 16 + lrow) * 136 + kk]);
      const bf16x8 a1 = *(const bf16x8*)(&As[1][(wave * 16 + lrow) * 136 + kk]);
#pragma unroll
      for (int ct = 0; ct < 4; ++ct) {
        const bf16x8 b0 = *(const bf16x8*)(&Bs[0][(ct * 16 + lrow) * 136 + kk]);
        const bf16x8 b1 = *(const bf16x8*)(&Bs[1][(ct * 16 + lrow) * 136 + kk]);
        acc[0][ct] = __builtin_amdgcn_mfma_f32_16x16x32_bf16(a0, b0, acc[0][ct], 0, 0, 0);
        acc[1][ct] = __builtin_amdgcn_mfma_f32_16x16x32_bf16(a1, b1, acc[1][ct], 0, 0, 0);
      }
    }

#pragma unroll
    for (int ct = 0; ct < 4; ++ct) {
      const int mc = sc * 64 + ct * 16 + lrow;   // col index within chunk (0..255)
      const int m = jb + mc;
      const int rm = m >> 5, cm = m & 31;
      const float im0 = rsc[0][mc], im1 = rsc[1][mc], im2 = rsc[2][mc];
#pragma unroll
      for (int reg = 0; reg < 4; ++reg) {
        const int nr = wave * 16 + kq * 4 + reg;  // row within tile (0..63)
        const int n = i0 + nr;
        const int rn = n >> 5, cn = n & 31;
        const float g = er[iabs_(rn - rm)] * er[iabs_(cn - cm)];
        const float fm = alpha * (1.f - g);
        const float c0 = acc[0][ct][reg];
        const float c1 = acc[1][ct][reg];
        const float e0 = __expf(fm * c0);
        const float e1 = __expf(fm * c1);
        const float e2 = __expf(fm * 0.5f * (c0 + c1));
        const float q0 = e0 * e0 * rsr[0][nr] * im0;
        const float q1 = e1 * e1 * rsr[1][nr] * im1;
        const float q2 = e2 * e2 * rsr[2][nr] * im2;
        INSERT3(q0, tA[0][reg], tB[0][reg], tC[0][reg]);
        INSERT3(q1, tA[1][reg], tB[1][reg], tC[1][reg]);
        INSERT3(q2, tA[2][reg], tB[2][reg], tC[2][reg]);
      }
    }
  }

  // merge across the 16 col-lanes (they hold the same rows)
#pragma unroll
  for (int off = 1; off < 16; off <<= 1)
#pragma unroll
    for (int ch = 0; ch < 3; ++ch)
#pragma unroll
      for (int reg = 0; reg < 4; ++reg) {
        const float b0 = __shfl_xor(tA[ch][reg], off, 64);
        const float b1 = __shfl_xor(tB[ch][reg], off, 64);
        const float b2 = __shfl_xor(tC[ch][reg], off, 64);
        MERGE3(tA[ch][reg], tB[ch][reg], tC[ch][reg], b0, b1, b2);
      }

  if (lrow == 0) {
#pragma unroll
    for (int ch = 0; ch < 3; ++ch)
#pragma unroll
      for (int reg = 0; reg < 4; ++reg) {
        const int n = i0 + wave * 16 + kq * 4 + reg;
        const size_t base = ((((size_t)b * NP + n) * 3 + ch) * 4 + cchunk) * 3;
        pbuf[base + 0] = tA[ch][reg];
        pbuf[base + 1] = tB[ch][reg];
        pbuf[base + 2] = tC[ch][reg];
      }
  }
}

// ---------------------------------------------------------------------------
// K5: merge the 4 per-colchunk top-3 partials and scatter to output.
// grid (32), block 256 — one thread per (b, n).
// ---------------------------------------------------------------------------
__global__ __launch_bounds__(256) void k5_merge(const float* __restrict__ pbuf,
                                                float* __restrict__ out) {
  const int tau = blockIdx.x * 256 + threadIdx.x;   // 0..8191
  const int b = tau >> 10;
  const int n = tau & (NP - 1);
  const int rn = n >> 5, cn = n & 31;

  float f0[3], f1[3], f2[3];
#pragma unroll
  for (int ch = 0; ch < 3; ++ch) {
    const size_t base = (((size_t)tau * 3 + ch) * 4) * 3;
    f0[ch] = pbuf[base + 0];
    f1[ch] = pbuf[base + 1];
    f2[ch] = pbuf[base + 2];
#pragma unroll
    for (int p = 1; p < 4; ++p) {
      const float b0 = pbuf[base + p * 3 + 0];
      const float b1 = pbuf[base + p * 3 + 1];
      const float b2 = pbuf[base + p * 3 + 2];
      MERGE3(f0[ch], f1[ch], f2[ch], b0, b1, b2);
    }
  }

  // scatter: channel 0 -> (2r,2c); 1 -> (2r+1,2c+1); 2 -> (2r,2c+1) and (2r+1,2c)
  float* ob = out + (size_t)b * 3 * (NH * NW);
  const int i00 = ((rn << 1) * NW) + (cn << 1);
#pragma unroll
  for (int tt = 0; tt < 3; ++tt) {
    float* op = ob + (size_t)tt * (NH * NW);
    const float r0 = (tt == 0) ? f0[0] : (tt == 1) ? f1[0] : f2[0];
    const float r1 = (tt == 0) ? f0[1] : (tt == 1) ? f1[1] : f2[1];
    const float r2 = (tt == 0) ? f0[2] : (tt == 1) ? f1[2] : f2[2];
    op[i00] = r0;            // (2r, 2c)
    op[i00 + NW + 1] = r1;   // (2r+1, 2c+1)
    op[i00 + 1] = r2;        // (2r, 2c+1)
    op[i00 + NW] = r2;       // (2r+1, 2c)
  }
}

extern "C" void kernel_launch(void* const* d_in, const int* in_sizes, int n_in,
                              void* d_out, int out_size, void* d_ws, size_t ws_size,
                              hipStream_t stream) {
  const float* x = (const float*)d_in[0];
  const float* alpha = (const float*)d_in[1];
  float* out = (float*)d_out;
  char* ws = (char*)d_ws;

  float* rsum = (float*)(ws + RSUM_OFF_B);
  float* pbuf = (float*)(ws + PBUF_OFF_B);
  __hip_bfloat16* xd = (__hip_bfloat16*)(ws + XD_OFF_B);

  hipMemsetAsync(rsum, 0, (size_t)NB * 3 * NP * sizeof(float), stream);
  k1_norm<<<dim3(16, 2, NB), 256, 0, stream>>>(x, xd);
  k2_sums<<<dim3(4, 16, NB), 256, 0, stream>>>((const ushort*)xd, alpha, rsum);
  k4_topk<<<dim3(4, 16, NB), 256, 0, stream>>>((const ushort*)xd, alpha, rsum, pbuf);
  k5_merge<<<dim3(32), 256, 0, stream>>>(pbuf, out);
}

// Round 4
// 111.474 us; speedup vs baseline: 1.8356x; 1.0684x over previous
//
#include <hip/hip_runtime.h>
#include <hip/hip_bf16.h>
#include <math.h>

// Problem constants
#define NB 8      // batch
#define NC 128    // channels
#define NH 64     // height
#define NW 64     // width
#define NP 1024   // npatch (32x32)
#define TWO_SIG2 5.12f      // 2*(0.05*32)^2
#define LOG2E 1.44269504089f

// ws layout (bytes):
//   psum : [NB][3][4cc][NP] fp32            = 384 KB  (partial exp row-sums)
//   pbuf : [NB*NP][3ch][4 part][3] fp32     = 1.18 MB (top-3 partials)
//   xd   : [NB*2][NP][NC] bf16              = 4 MB
static const size_t PSUM_OFF_B = 0;
static const size_t PBUF_OFF_B = (size_t)NB * 3 * 4 * NP * 4;
static const size_t XD_OFF_B   = PBUF_OFF_B + (size_t)NB * NP * 3 * 4 * 3 * 4;

typedef __bf16 bf16x8 __attribute__((ext_vector_type(8)));
typedef float f32x4 __attribute__((ext_vector_type(4)));

__device__ __forceinline__ int iabs_(int v) { return v < 0 ? -v : v; }

// Insert v into sorted-descending triple (A >= B >= C): 3 instrs via med3
#define INSERT3(v, A, Bq, Cq)                          \
  {                                                    \
    const float _na = fmaxf(A, (v));                   \
    const float _nb = __builtin_amdgcn_fmed3f(A, Bq, (v)); \
    Cq = __builtin_amdgcn_fmed3f(Bq, Cq, (v));         \
    A = _na;                                           \
    Bq = _nb;                                          \
  }

// Merge two sorted-descending triples (a <- top3 of union)
#define MERGE3(a0, a1, a2, b0, b1, b2)       \
  {                                          \
    const float _x1 = fmaxf(a0, b0);         \
    const float _y1 = fminf(a0, b0);         \
    const float _x2 = fmaxf(a1, b1);         \
    const float _z  = fmaxf(a2, b2);         \
    a0 = _x1;                                \
    a1 = fmaxf(_y1, _x2);                    \
    a2 = fmaxf(fminf(_y1, _x2), _z);         \
  }

// ---------------------------------------------------------------------------
// K1: L2-normalize over channels at the two diagonal pixels of each 2x2 patch
//     and write transposed xd[b][p][n][c] (c contiguous) as bf16.
// grid (16 chunks of 64 patches, p=2, b=8), block 256
// ---------------------------------------------------------------------------
__global__ __launch_bounds__(256) void k1_norm(const float* __restrict__ x,
                                               __hip_bfloat16* __restrict__ xd) {
  __shared__ __align__(16) float tile[NC * 65];
  const int chunk = blockIdx.x;
  const int p = blockIdx.y;
  const int b = blockIdx.z;
  const int t = threadIdx.x;
  const int pix = t & 63;
  const int cw = t >> 6;
  const int nbase = chunk * 64;

  {
    const int n = nbase + pix;
    const int i = ((n >> 5) << 1) + p;   // 2r + p
    const int jf = (n & 31);             // float2 index: cols (2jf, 2jf+1)
    const float* xb = x + (size_t)b * NC * NH * NW + (size_t)i * NW;
    for (int cc = 0; cc < 32; ++cc) {
      const int c = (cc << 2) + cw;
      const float2 v2 = ((const float2*)(xb + (size_t)c * NH * NW))[jf];
      tile[c * 65 + pix] = (p == 0) ? v2.x : v2.y;
    }
  }
  __syncthreads();

  const int lane = t & 63;
  const int w = t >> 6;
  for (int pg = 0; pg < 16; ++pg) {
    const int pixel = (pg << 2) + w;     // each wave owns one pixel (128 channels)
    const float v0 = tile[lane * 65 + pixel];
    const float v1 = tile[(lane + 64) * 65 + pixel];
    float ss = v0 * v0 + v1 * v1;
#pragma unroll
    for (int m = 32; m >= 1; m >>= 1) ss += __shfl_xor(ss, m, 64);
    const float inv = 1.0f / fmaxf(sqrtf(ss), 1e-12f);
    __hip_bfloat16* xr = xd + ((size_t)((b * 2 + p) * NP) + nbase + pixel) * NC;
    xr[lane] = __float2bfloat16(v0 * inv);
    xr[lane + 64] = __float2bfloat16(v1 * inv);
  }
}

// ---------------------------------------------------------------------------
// K2: fused corr (MFMA, registers) -> mask -> exp2 -> PARTIAL row sums.
// No atomics: block (cchunk,rowtile,b) writes psum[b][ch][cchunk][n].
// grid (4 colchunk, 16 rowtile, 8 b), block 256 (4 waves; wave owns 16 rows)
// ---------------------------------------------------------------------------
__global__ __launch_bounds__(256) void k2_sums(const ushort* __restrict__ xd,
                                               const float* __restrict__ alpha_p,
                                               float* __restrict__ psum) {
  __shared__ __align__(16) __bf16 As[2][64 * 136];
  __shared__ __align__(16) __bf16 Bs[2][64 * 136];
  __shared__ float er[32];    // gaussian table
  __shared__ float erA[32];   // alpha*log2e * er
  const int t = threadIdx.x;
  const float K = (*alpha_p) * LOG2E;
  if (t < 32) {
    const float e = __expf(-(float)(t * t) / TWO_SIG2);
    er[t] = e;
    erA[t] = K * e;
  }

  const int cchunk = blockIdx.x;
  const int rowtile = blockIdx.y;
  const int b = blockIdx.z;
  const int i0 = rowtile << 6;
  const int jb = cchunk << 8;

#pragma unroll
  for (int pl = 0; pl < 2; ++pl) {
    const float4* ga = (const float4*)(xd + ((size_t)(b * 2 + pl) * NP + i0) * NC);
#pragma unroll
    for (int it = 0; it < 4; ++it) {
      const int f = (it << 8) + t;
      const int r = f >> 4, q = f & 15;
      *(float4*)(&As[pl][r * 136 + q * 8]) = ga[f];
    }
  }

  const int wave = t >> 6;
  const int lane = t & 63;
  const int lrow = lane & 15;
  const int kq = lane >> 4;

  float sums[3][4];
#pragma unroll
  for (int ch = 0; ch < 3; ++ch)
#pragma unroll
    for (int reg = 0; reg < 4; ++reg) sums[ch][reg] = 0.f;

  for (int sc = 0; sc < 4; ++sc) {
    const int j0 = jb + (sc << 6);
    __syncthreads();
#pragma unroll
    for (int pl = 0; pl < 2; ++pl) {
      const float4* gb = (const float4*)(xd + ((size_t)(b * 2 + pl) * NP + j0) * NC);
#pragma unroll
      for (int it = 0; it < 4; ++it) {
        const int f = (it << 8) + t;
        const int r = f >> 4, q = f & 15;
        *(float4*)(&Bs[pl][r * 136 + q * 8]) = gb[f];
      }
    }
    __syncthreads();

    f32x4 acc[2][4];
#pragma unroll
    for (int pl = 0; pl < 2; ++pl)
#pragma unroll
      for (int ct = 0; ct < 4; ++ct)
#pragma unroll
        for (int u = 0; u < 4; ++u) acc[pl][ct][u] = 0.f;

#pragma unroll
    for (int kc = 0; kc < 4; ++kc) {
      const int kk = kc * 32 + (kq << 3);
      const bf16x8 a0 = *(const bf16x8*)(&As[0][(wave * 16 + lrow) * 136 + kk]);
      const bf16x8 a1 = *(const bf16x8*)(&As[1][(wave * 16 + lrow) * 136 + kk]);
#pragma unroll
      for (int ct = 0; ct < 4; ++ct) {
        const bf16x8 b0 = *(const bf16x8*)(&Bs[0][(ct * 16 + lrow) * 136 + kk]);
        const bf16x8 b1 = *(const bf16x8*)(&Bs[1][(ct * 16 + lrow) * 136 + kk]);
        acc[0][ct] = __builtin_amdgcn_mfma_f32_16x16x32_bf16(a0, b0, acc[0][ct], 0, 0, 0);
        acc[1][ct] = __builtin_amdgcn_mfma_f32_16x16x32_bf16(a1, b1, acc[1][ct], 0, 0, 0);
      }
    }

    // mask + exp2 + accumulate partial row sums
#pragma unroll
    for (int ct = 0; ct < 4; ++ct) {
      const int m = j0 + ct * 16 + lrow;
      const int rm = m >> 5, cm = m & 31;
#pragma unroll
      for (int reg = 0; reg < 4; ++reg) {
        const int n = i0 + wave * 16 + kq * 4 + reg;
        const int rn = n >> 5, cn = n & 31;
        // fm2 = log2e*alpha*(1-g); exact 0 on the diagonal
        const float fm2 = fmaf(-erA[iabs_(rn - rm)], er[iabs_(cn - cm)], K);
        const float g0 = fm2 * acc[0][ct][reg];
        const float g1 = fm2 * acc[1][ct][reg];
        sums[0][reg] += exp2f(g0);
        sums[1][reg] += exp2f(g1);
        sums[2][reg] += exp2f(0.5f * (g0 + g1));
      }
    }
  }

  // reduce across the 16 col-lanes (same rows)
#pragma unroll
  for (int off = 1; off < 16; off <<= 1)
#pragma unroll
    for (int ch = 0; ch < 3; ++ch)
#pragma unroll
      for (int reg = 0; reg < 4; ++reg)
        sums[ch][reg] += __shfl_xor(sums[ch][reg], off, 64);

  if (lrow == 0) {
#pragma unroll
    for (int ch = 0; ch < 3; ++ch)
#pragma unroll
      for (int reg = 0; reg < 4; ++reg) {
        const int n = i0 + wave * 16 + kq * 4 + reg;
        psum[(((size_t)b * 3 + ch) * 4 + cchunk) * NP + n] = sums[ch][reg];
      }
  }
}

// ---------------------------------------------------------------------------
// K4: fused corr recompute -> mask -> exp2 -> z = E^2 * ir_m -> online top-3
// per row per channel (ir_n applied to the winners at the end).
// grid (4 colchunk, 16 rowtile, 8 b), block 256
// ---------------------------------------------------------------------------
__global__ __launch_bounds__(256) void k4_topk(const ushort* __restrict__ xd,
                                               const float* __restrict__ alpha_p,
                                               const float* __restrict__ psum,
                                               float* __restrict__ pbuf) {
  __shared__ __align__(16) __bf16 As[2][64 * 136];
  __shared__ __align__(16) __bf16 Bs[2][64 * 136];
  __shared__ float er[32];
  __shared__ float erA[32];
  __shared__ float rsr[3][64];    // 1/rowsum over this block's rows
  __shared__ float rsc[3][256];   // 1/rowsum over this block's cols
  const int t = threadIdx.x;
  const float K = (*alpha_p) * LOG2E;
  if (t < 32) {
    const float e = __expf(-(float)(t * t) / TWO_SIG2);
    er[t] = e;
    erA[t] = K * e;
  }

  const int cchunk = blockIdx.x;
  const int rowtile = blockIdx.y;
  const int b = blockIdx.z;
  const int i0 = rowtile << 6;
  const int jb = cchunk << 8;

  if (t < 192) {
    const int ch = t >> 6, r = t & 63;
    const float* pp = psum + ((size_t)b * 3 + ch) * 4 * NP + i0 + r;
    rsr[ch][r] = 1.0f / (pp[0] + pp[NP] + pp[2 * NP] + pp[3 * NP]);
  }
#pragma unroll
  for (int ch = 0; ch < 3; ++ch) {
    const float* pp = psum + ((size_t)b * 3 + ch) * 4 * NP + jb + t;
    rsc[ch][t] = 1.0f / (pp[0] + pp[NP] + pp[2 * NP] + pp[3 * NP]);
  }

#pragma unroll
  for (int pl = 0; pl < 2; ++pl) {
    const float4* ga = (const float4*)(xd + ((size_t)(b * 2 + pl) * NP + i0) * NC);
#pragma unroll
    for (int it = 0; it < 4; ++it) {
      const int f = (it << 8) + t;
      const int r = f >> 4, q = f & 15;
      *(float4*)(&As[pl][r * 136 + q * 8]) = ga[f];
    }
  }

  const int wave = t >> 6;
  const int lane = t & 63;
  const int lrow = lane & 15;
  const int kq = lane >> 4;

  float tA[3][4], tB[3][4], tC[3][4];
#pragma unroll
  for (int ch = 0; ch < 3; ++ch)
#pragma unroll
    for (int reg = 0; reg < 4; ++reg) { tA[ch][reg] = 0.f; tB[ch][reg] = 0.f; tC[ch][reg] = 0.f; }

  for (int sc = 0; sc < 4; ++sc) {
    const int j0 = jb + (sc << 6);
    __syncthreads();
#pragma unroll
    for (int pl = 0; pl < 2; ++pl) {
      const float4* gb = (const float4*)(xd + ((size_t)(b * 2 + pl) * NP + j0) * NC);
#pragma unroll
      for (int it = 0; it < 4; ++it) {
        const int f = (it << 8) + t;
        const int r = f >> 4, q = f & 15;
        *(float4*)(&Bs[pl][r * 136 + q * 8]) = gb[f];
      }
    }
    __syncthreads();

    f32x4 acc[2][4];
#pragma unroll
    for (int pl = 0; pl < 2; ++pl)
#pragma unroll
      for (int ct = 0; ct < 4; ++ct)
#pragma unroll
        for (int u = 0; u < 4; ++u) acc[pl][ct][u] = 0.f;

#pragma unroll
    for (int kc = 0; kc < 4; ++kc) {
      const int kk = kc * 32 + (kq << 3);
      const bf16x8 a0 = *(const bf16x8*)(&As[0][(wave * 16 + lrow) * 136 + kk]);
      const bf16x8 a1 = *(const bf16x8*)(&As[1][(wave * 16 + lrow) * 136 + kk]);
#pragma unroll
      for (int ct = 0; ct < 4; ++ct) {
        const bf16x8 b0 = *(const bf16x8*)(&Bs[0][(ct * 16 + lrow) * 136 + kk]);
        const bf16x8 b1 = *(const bf16x8*)(&Bs[1][(ct * 16 + lrow) * 136 + kk]);
        acc[0][ct] = __builtin_amdgcn_mfma_f32_16x16x32_bf16(a0, b0, acc[0][ct], 0, 0, 0);
        acc[1][ct] = __builtin_amdgcn_mfma_f32_16x16x32_bf16(a1, b1, acc[1][ct], 0, 0, 0);
      }
    }

#pragma unroll
    for (int ct = 0; ct < 4; ++ct) {
      const int mc = sc * 64 + ct * 16 + lrow;   // col index within chunk (0..255)
      const int m = jb + mc;
      const int rm = m >> 5, cm = m & 31;
      const float im0 = rsc[0][mc], im1 = rsc[1][mc], im2 = rsc[2][mc];
#pragma unroll
      for (int reg = 0; reg < 4; ++reg) {
        const int nr = wave * 16 + kq * 4 + reg;  // row within tile (0..63)
        const int n = i0 + nr;
        const int rn = n >> 5, cn = n & 31;
        const float fm2 = fmaf(-erA[iabs_(rn - rm)], er[iabs_(cn - cm)], K);
        const float g0 = fm2 * acc[0][ct][reg];
        const float g1 = fm2 * acc[1][ct][reg];
        const float e0 = exp2f(g0);
        const float e1 = exp2f(g1);
        const float e2 = exp2f(0.5f * (g0 + g1));
        const float q0 = e0 * e0 * im0;   // ir_n folded in at the end
        const float q1 = e1 * e1 * im1;
        const float q2 = e2 * e2 * im2;
        INSERT3(q0, tA[0][reg], tB[0][reg], tC[0][reg]);
        INSERT3(q1, tA[1][reg], tB[1][reg], tC[1][reg]);
        INSERT3(q2, tA[2][reg], tB[2][reg], tC[2][reg]);
      }
    }
  }

  // merge across the 16 col-lanes (they hold the same rows)
#pragma unroll
  for (int off = 1; off < 16; off <<= 1)
#pragma unroll
    for (int ch = 0; ch < 3; ++ch)
#pragma unroll
      for (int reg = 0; reg < 4; ++reg) {
        const float b0 = __shfl_xor(tA[ch][reg], off, 64);
        const float b1 = __shfl_xor(tB[ch][reg], off, 64);
        const float b2 = __shfl_xor(tC[ch][reg], off, 64);
        MERGE3(tA[ch][reg], tB[ch][reg], tC[ch][reg], b0, b1, b2);
      }

  if (lrow == 0) {
#pragma unroll
    for (int ch = 0; ch < 3; ++ch)
#pragma unroll
      for (int reg = 0; reg < 4; ++reg) {
        const int nr = wave * 16 + kq * 4 + reg;
        const int n = i0 + nr;
        const float irn = rsr[ch][nr];
        const size_t base = ((((size_t)b * NP + n) * 3 + ch) * 4 + cchunk) * 3;
        pbuf[base + 0] = tA[ch][reg] * irn;
        pbuf[base + 1] = tB[ch][reg] * irn;
        pbuf[base + 2] = tC[ch][reg] * irn;
      }
  }
}

// ---------------------------------------------------------------------------
// K5: merge the 4 per-colchunk top-3 partials and scatter to output.
// grid (32), block 256 — one thread per (b, n).
// ---------------------------------------------------------------------------
__global__ __launch_bounds__(256) void k5_merge(const float* __restrict__ pbuf,
                                                float* __restrict__ out) {
  const int tau = blockIdx.x * 256 + threadIdx.x;   // 0..8191
  const int b = tau >> 10;
  const int n = tau & (NP - 1);
  const int rn = n >> 5, cn = n & 31;

  float f0[3], f1[3], f2[3];
#pragma unroll
  for (int ch = 0; ch < 3; ++ch) {
    const size_t base = (((size_t)tau * 3 + ch) * 4) * 3;
    f0[ch] = pbuf[base + 0];
    f1[ch] = pbuf[base + 1];
    f2[ch] = pbuf[base + 2];
#pragma unroll
    for (int p = 1; p < 4; ++p) {
      const float b0 = pbuf[base + p * 3 + 0];
      const float b1 = pbuf[base + p * 3 + 1];
      const float b2 = pbuf[base + p * 3 + 2];
      MERGE3(f0[ch], f1[ch], f2[ch], b0, b1, b2);
    }
  }

  // scatter: channel 0 -> (2r,2c); 1 -> (2r+1,2c+1); 2 -> (2r,2c+1) and (2r+1,2c)
  float* ob = out + (size_t)b * 3 * (NH * NW);
  const int i00 = ((rn << 1) * NW) + (cn << 1);
#pragma unroll
  for (int tt = 0; tt < 3; ++tt) {
    float* op = ob + (size_t)tt * (NH * NW);
    const float r0 = (tt == 0) ? f0[0] : (tt == 1) ? f1[0] : f2[0];
    const float r1 = (tt == 0) ? f0[1] : (tt == 1) ? f1[1] : f2[1];
    const float r2 = (tt == 0) ? f0[2] : (tt == 1) ? f1[2] : f2[2];
    op[i00] = r0;            // (2r, 2c)
    op[i00 + NW + 1] = r1;   // (2r+1, 2c+1)
    op[i00 + 1] = r2;        // (2r, 2c+1)
    op[i00 + NW] = r2;       // (2r+1, 2c)
  }
}

extern "C" void kernel_launch(void* const* d_in, const int* in_sizes, int n_in,
                              void* d_out, int out_size, void* d_ws, size_t ws_size,
                              hipStream_t stream) {
  const float* x = (const float*)d_in[0];
  const float* alpha = (const float*)d_in[1];
  float* out = (float*)d_out;
  char* ws = (char*)d_ws;

  float* psum = (float*)(ws + PSUM_OFF_B);
  float* pbuf = (float*)(ws + PBUF_OFF_B);
  __hip_bfloat16* xd = (__hip_bfloat16*)(ws + XD_OFF_B);

  k1_norm<<<dim3(16, 2, NB), 256, 0, stream>>>(x, xd);
  k2_sums<<<dim3(4, 16, NB), 256, 0, stream>>>((const ushort*)xd, alpha, psum);
  k4_topk<<<dim3(4, 16, NB), 256, 0, stream>>>((const ushort*)xd, alpha, psum, pbuf);
  k5_merge<<<dim3(32), 256, 0, stream>>>(pbuf, out);
}